// Round 4
// baseline (45.436 us; speedup 1.0000x reference)
//
#include <hip/hip_runtime.h>
#include <math.h>

#define EPSF 1e-8f

constexpr int B   = 512;
constexpr int F   = 256;        // floats per row
constexpr int NF4 = F / 4;      // 64 float4 per row
constexpr int TPB = 512;        // 8 waves
constexpr int G   = 4;          // output rows per block
constexpr int CH  = 64;         // j-rows per chunk
constexpr int NCH = B / CH;     // 8 chunks

// ---------------- main kernel: 128 blocks x 512 threads --------------------
// Block b owns output rows i0..i0+3. Phase 1 computes cosrow[4][512] in LDS
// via a double-buffered chunked pass over all j-rows (no global cos matrix).
// Phase 2: wave w handles row i0+w: ballot-compacted sim set + pair hinge sum.
__global__ __launch_bounds__(TPB) void hinge_main(
    const int* __restrict__ ids,
    const float* __restrict__ feats,
    float* __restrict__ rowloss,
    int* __restrict__ rowvalid)
{
    // phys slot = k4 ^ (row & 7): spreads lane-varying-row ds_read_b128
    // across all 8 16B bank-group slots (G4 swizzle).
    __shared__ float4 Bs[2][CH][NF4];     // 128 KB
    __shared__ float4 As[G][NF4];         // 4 KB (linear; reads are wave-uniform)
    __shared__ float  cosrow[G][B];       // 8 KB
    __shared__ float  vals[G][B];         // 8 KB
    __shared__ float  part[G][4][64];     // 4 KB
    __shared__ float  part_ss[4][64];     // 1 KB
    __shared__ float  invi_s[G];

    const int tid = threadIdx.x;
    const int w = tid >> 6, l = tid & 63;
    const int ip = w >> 2;                // i-pair: waves 0-3 -> i{0,1}, 4-7 -> i{2,3}
    const int kq = w & 3;                 // k-quarter (64 floats)
    const int i0 = blockIdx.x * G;
    const float4* fg = (const float4*)feats;

    // ---- prologue: stage A rows + exact fp32 inverse norms of the 4 i-rows
    if (w < G) {
        float4 a = fg[(size_t)(i0 + w) * NF4 + l];
        As[w][l] = a;
        float ss = a.x*a.x + a.y*a.y + a.z*a.z + a.w*a.w;
        #pragma unroll
        for (int off = 32; off > 0; off >>= 1) ss += __shfl_down(ss, off);
        if (l == 0) invi_s[w] = 1.f / fmaxf(sqrtf(ss + EPSF), EPSF);
    }
    // stage chunk 0 (coalesced global read, swizzled LDS write)
    #pragma unroll
    for (int m = 0; m < 8; ++m) {
        int r = w * 8 + m;
        Bs[0][r][l ^ (r & 7)] = fg[(size_t)r * NF4 + l];
    }
    __syncthreads();

    // ---- phase 1: 8 chunks, double-buffered (issue-early / write-late)
    for (int c = 0; c < NCH; ++c) {
        const int cb = c & 1, nb = cb ^ 1;
        float4 st[8];
        if (c + 1 < NCH) {                       // issue next-chunk loads early
            #pragma unroll
            for (int m = 0; m < 8; ++m) {
                int r = w * 8 + m;
                st[m] = fg[(size_t)((c + 1) * CH + r) * NF4 + l];
            }
        }
        // compute: lane l <-> j-row l of chunk; 2 i-accumulators + j-norm
        float4 acc0 = {0,0,0,0}, acc1 = {0,0,0,0}, asq = {0,0,0,0};
        #pragma unroll
        for (int t = 0; t < 16; ++t) {
            const int k4 = kq * 16 + t;
            float4 b  = Bs[cb][l][k4 ^ (l & 7)];
            float4 a0 = As[2*ip][k4];            // wave-uniform -> broadcast
            float4 a1 = As[2*ip+1][k4];
            acc0.x += a0.x*b.x; acc0.y += a0.y*b.y; acc0.z += a0.z*b.z; acc0.w += a0.w*b.w;
            acc1.x += a1.x*b.x; acc1.y += a1.y*b.y; acc1.z += a1.z*b.z; acc1.w += a1.w*b.w;
            if (ip == 0) { asq.x += b.x*b.x; asq.y += b.y*b.y; asq.z += b.z*b.z; asq.w += b.w*b.w; }
        }
        if (c + 1 < NCH) {                       // write-late into other buffer
            #pragma unroll
            for (int m = 0; m < 8; ++m) {
                int r = w * 8 + m;
                Bs[nb][r][l ^ (r & 7)] = st[m];
            }
        }
        part[2*ip][kq][l]   = acc0.x + acc0.y + acc0.z + acc0.w;
        part[2*ip+1][kq][l] = acc1.x + acc1.y + acc1.z + acc1.w;
        if (ip == 0) part_ss[kq][l] = asq.x + asq.y + asq.z + asq.w;
        __syncthreads();
        if (w < G) {                             // combine k-quarters -> cosrow
            float cv = part[w][0][l] + part[w][1][l] + part[w][2][l] + part[w][3][l];
            float ss = part_ss[0][l] + part_ss[1][l] + part_ss[2][l] + part_ss[3][l];
            float invj = 1.f / fmaxf(sqrtf(ss + EPSF), EPSF);
            cosrow[w][c * CH + l] = cv * invi_s[w] * invj;
        }
        __syncthreads();                         // protect part[] reuse
    }

    // ---- phase 2: wave w (< G) handles row i = i0 + w; waves 4-7 done
    if (w < G) {
        const int i = i0 + w;
        const int4 idi = ((const int4*)ids)[i];
        unsigned long long sm[8];
        int dd_[8];
        #pragma unroll
        for (int cc = 0; cc < 8; ++cc) {
            int j = cc * 64 + l;
            int4 idj = ((const int4*)ids)[j];
            int d = abs(idi.x-idj.x) + abs(idi.y-idj.y)
                  + abs(idi.z-idj.z) + abs(idi.w-idj.w);
            dd_[cc] = d;
            sm[cc] = __ballot(d == 0 && j != i);
        }
        // deterministic ballot compaction of sim cos values
        int off = 0;
        #pragma unroll
        for (int cc = 0; cc < 8; ++cc) {
            unsigned long long m = sm[cc];
            if ((m >> l) & 1ull) {
                int pos = off + (int)__popcll(m & ((1ull << l) - 1ull));
                vals[w][pos] = cosrow[w][cc * 64 + l];
            }
            off += (int)__popcll(m);
        }
        const int ns = off;
        __threadfence_block();                   // order vals writes before reads
        float bk[8];                             // -inf sentinel for non-dif k
        #pragma unroll
        for (int cc = 0; cc < 8; ++cc)
            bk[cc] = (dd_[cc] > 0) ? 0.15f * (float)dd_[cc] + cosrow[w][cc*64 + l]
                                   : -1e30f;
        float s = 0.f;
        for (int t = 0; t < ns; ++t) {           // ~31 iters, broadcast LDS read
            float a = vals[w][t];
            #pragma unroll
            for (int cc = 0; cc < 8; ++cc) s += fmaxf(0.f, bk[cc] - a);
        }
        #pragma unroll
        for (int off2 = 32; off2 > 0; off2 >>= 1) s += __shfl_down(s, off2);
        if (l == 0) {
            int nd  = (B - 1) - ns;              // every j != i is sim xor dif
            int cnt = ns * nd;
            rowloss[i]  = (cnt > 0) ? s / (float)cnt : 0.f;
            rowvalid[i] = (cnt > 0) ? 1 : 0;
        }
    }
}

// ---------------- finalize: 1 block, mean over valid rows ------------------
__global__ __launch_bounds__(256) void finalize_kernel(
    const float* __restrict__ rowloss, const int* __restrict__ rowvalid,
    float* __restrict__ out)
{
    const int tid  = threadIdx.x;
    const int lane = tid & 63;
    const int wid  = tid >> 6;
    __shared__ float sb[4], vb[4];

    float s = rowloss[tid] + rowloss[tid + 256];
    float v = (float)(rowvalid[tid] + rowvalid[tid + 256]);
    #pragma unroll
    for (int off = 32; off > 0; off >>= 1) {
        s += __shfl_down(s, off);
        v += __shfl_down(v, off);
    }
    if (lane == 0) { sb[wid] = s; vb[wid] = v; }
    __syncthreads();
    if (tid == 0) {
        float ts = sb[0] + sb[1] + sb[2] + sb[3];
        float tv = vb[0] + vb[1] + vb[2] + vb[3];
        out[0] = ts / fmaxf(tv, 1.f);
    }
}

extern "C" void kernel_launch(void* const* d_in, const int* in_sizes, int n_in,
                              void* d_out, int out_size, void* d_ws, size_t ws_size,
                              hipStream_t stream) {
    const int*   ids   = (const int*)d_in[0];
    const float* feats = (const float*)d_in[1];
    float* out = (float*)d_out;

    char* ws = (char*)d_ws;
    float* rowloss  = (float*)ws;                 // 2 KB
    int*   rowvalid = (int*)(ws + 2048);          // 2 KB

    hipLaunchKernelGGL(hinge_main, dim3(B / G), dim3(TPB), 0, stream,
                       ids, feats, rowloss, rowvalid);
    hipLaunchKernelGGL(finalize_kernel, dim3(1), dim3(256), 0, stream,
                       rowloss, rowvalid, out);
}

// Round 5
// 33.876 us; speedup vs baseline: 1.3412x; 1.3412x over previous
//
#include <hip/hip_runtime.h>
#include <math.h>

#define EPSF 1e-8f

constexpr int B   = 512;
constexpr int F   = 256;
constexpr int NF4 = F / 4;      // 64 float4 per row
constexpr int TPB = 512;        // 8 waves; thread t owns j-row t

// 256 blocks x 512 threads. Block b computes rows i0=2b, i0+1 end-to-end:
// cos row via per-thread dot (A-rows are block-uniform -> scalar loads),
// ballot-compacted sim set, pair hinge sum, then last-block finalize.
__global__ __launch_bounds__(TPB, 2) void hinge_all(
    const int* __restrict__ ids,
    const float* __restrict__ feats,
    float* __restrict__ rowloss,
    int* __restrict__ rowvalid,
    unsigned int* __restrict__ ticket,
    float* __restrict__ out)
{
    const int tid = threadIdx.x;          // == j-row this thread owns
    const int w = tid >> 6, l = tid & 63;
    const int i0 = blockIdx.x * 2, i1 = i0 + 1;

    __shared__ float ssi[2];
    __shared__ float vals0[B], vals1[B];
    __shared__ unsigned long long cm0[8], cm1[8];
    __shared__ int coff0[9], coff1[9];
    __shared__ float red0[8], red1[8];
    __shared__ int lastflag;

    // ---- j-scan: dot(i0,j), dot(i1,j), ||j||^2. No LDS in the hot loop.
    const float4* __restrict__ Bg = (const float4*)feats + (size_t)tid * NF4;
    const float4* __restrict__ A0 = (const float4*)feats + (size_t)i0 * NF4;
    const float4* __restrict__ A1 = (const float4*)feats + (size_t)i1 * NF4;

    float4 d0 = {0,0,0,0}, d1 = {0,0,0,0}, sq = {0,0,0,0};
    #pragma unroll 4
    for (int k = 0; k < NF4; ++k) {
        float4 b  = Bg[k];
        float4 a0 = A0[k];                // block-uniform -> s_load path
        float4 a1 = A1[k];
        d0.x += a0.x*b.x; d0.y += a0.y*b.y; d0.z += a0.z*b.z; d0.w += a0.w*b.w;
        d1.x += a1.x*b.x; d1.y += a1.y*b.y; d1.z += a1.z*b.z; d1.w += a1.w*b.w;
        sq.x += b.x*b.x;  sq.y += b.y*b.y;  sq.z += b.z*b.z;  sq.w += b.w*b.w;
    }
    const float dot0 = (d0.x + d0.y) + (d0.z + d0.w);
    const float dot1 = (d1.x + d1.y) + (d1.z + d1.w);
    const float ss   = (sq.x + sq.y) + (sq.z + sq.w);
    if (tid == i0) ssi[0] = ss;           // threads i0,i1 exist in every block
    if (tid == i1) ssi[1] = ss;
    __syncthreads();

    const float inv0 = 1.f / fmaxf(sqrtf(ssi[0] + EPSF), EPSF);
    const float inv1 = 1.f / fmaxf(sqrtf(ssi[1] + EPSF), EPSF);
    const float invj = 1.f / fmaxf(sqrtf(ss + EPSF), EPSF);
    const float cos0 = dot0 * inv0 * invj;
    const float cos1 = dot1 * inv1 * invj;

    // ---- id distances (ids arrive as int32, 4 per row)
    const int4 idj  = ((const int4*)ids)[tid];
    const int4 idi0 = ((const int4*)ids)[i0];
    const int4 idi1 = ((const int4*)ids)[i1];
    const int dd0 = abs(idi0.x-idj.x) + abs(idi0.y-idj.y)
                  + abs(idi0.z-idj.z) + abs(idi0.w-idj.w);
    const int dd1 = abs(idi1.x-idj.x) + abs(idi1.y-idj.y)
                  + abs(idi1.z-idj.z) + abs(idi1.w-idj.w);

    // ---- deterministic ballot-compaction of the two sim sets
    const unsigned long long m0 = __ballot(dd0 == 0 && tid != i0);
    const unsigned long long m1 = __ballot(dd1 == 0 && tid != i1);
    if (l == 0) { cm0[w] = m0; cm1[w] = m1; }
    __syncthreads();
    if (tid < 2) {
        const unsigned long long* cm = tid ? cm1 : cm0;
        int* co = tid ? coff1 : coff0;
        int a = 0;
        #pragma unroll
        for (int c = 0; c < 8; ++c) { co[c] = a; a += (int)__popcll(cm[c]); }
        co[8] = a;
    }
    __syncthreads();
    if (dd0 == 0 && tid != i0)
        vals0[coff0[w] + (int)__popcll(m0 & ((1ull << l) - 1ull))] = cos0;
    if (dd1 == 0 && tid != i1)
        vals1[coff1[w] + (int)__popcll(m1 & ((1ull << l) - 1ull))] = cos1;
    __syncthreads();

    // ---- pair hinge sums: thread t is negative candidate k=t (sentinel if sim)
    const int ns0 = coff0[8], ns1 = coff1[8];
    const float b0 = (dd0 > 0) ? 0.15f * (float)dd0 + cos0 : -1e30f;
    const float b1 = (dd1 > 0) ? 0.15f * (float)dd1 + cos1 : -1e30f;
    float s0 = 0.f, s1 = 0.f;
    for (int t = 0; t < ns0; ++t) s0 += fmaxf(0.f, b0 - vals0[t]);
    for (int t = 0; t < ns1; ++t) s1 += fmaxf(0.f, b1 - vals1[t]);

    #pragma unroll
    for (int o = 32; o > 0; o >>= 1) { s0 += __shfl_down(s0, o); s1 += __shfl_down(s1, o); }
    if (l == 0) { red0[w] = s0; red1[w] = s1; }
    __syncthreads();
    if (tid == 0) {
        float t0 = 0.f, t1 = 0.f;
        #pragma unroll
        for (int q = 0; q < 8; ++q) { t0 += red0[q]; t1 += red1[q]; }
        const int nd0 = (B - 1) - ns0, nd1 = (B - 1) - ns1;  // j!=i is sim xor dif
        const int c0 = ns0 * nd0, c1 = ns1 * nd1;
        rowloss[i0]  = c0 > 0 ? t0 / (float)c0 : 0.f;
        rowloss[i1]  = c1 > 0 ? t1 / (float)c1 : 0.f;
        rowvalid[i0] = c0 > 0 ? 1 : 0;
        rowvalid[i1] = c1 > 0 ? 1 : 0;
        __threadfence();                   // device-scope release of row stores
        unsigned int old = atomicAdd(ticket, 1u);
        lastflag = (old == 255u) ? 1 : 0;  // ticket memset to 0 each call
    }
    __syncthreads();
    if (!lastflag) return;

    // ---- last block: deterministic device-coherent reduce over all rows
    float fs = atomicAdd(&rowloss[tid], 0.f);          // L2-coherent read
    float fv = (float)atomicAdd(&rowvalid[tid], 0);
    #pragma unroll
    for (int o = 32; o > 0; o >>= 1) { fs += __shfl_down(fs, o); fv += __shfl_down(fv, o); }
    __syncthreads();                       // red[] reuse
    if (l == 0) { red0[w] = fs; red1[w] = fv; }
    __syncthreads();
    if (tid == 0) {
        float ts = 0.f, tv = 0.f;
        #pragma unroll
        for (int q = 0; q < 8; ++q) { ts += red0[q]; tv += red1[q]; }
        out[0] = ts / fmaxf(tv, 1.f);
    }
}

extern "C" void kernel_launch(void* const* d_in, const int* in_sizes, int n_in,
                              void* d_out, int out_size, void* d_ws, size_t ws_size,
                              hipStream_t stream) {
    const int*   ids   = (const int*)d_in[0];
    const float* feats = (const float*)d_in[1];
    float* out = (float*)d_out;

    char* ws = (char*)d_ws;
    float*        rowloss  = (float*)ws;                    // 2 KB
    int*          rowvalid = (int*)(ws + 2048);             // 2 KB
    unsigned int* ticket   = (unsigned int*)(ws + 4096);    // 4 B

    hipMemsetAsync(ticket, 0, sizeof(unsigned int), stream);   // graph-capturable node
    hipLaunchKernelGGL(hinge_all, dim3(256), dim3(TPB), 0, stream,
                       ids, feats, rowloss, rowvalid, ticket, out);
}

// Round 6
// 29.694 us; speedup vs baseline: 1.5301x; 1.1408x over previous
//
#include <hip/hip_runtime.h>
#include <math.h>

#define EPSF 1e-8f

constexpr int B   = 512;
constexpr int F   = 256;

using frag_ab = __attribute__((ext_vector_type(8))) short;   // 8 bf16
using f32x4   = __attribute__((ext_vector_type(4))) float;

__device__ __forceinline__ unsigned short f2bf(float f) {
    unsigned int u = __float_as_uint(f);
    unsigned int r = (u + 0x7fffu + ((u >> 16) & 1u)) >> 16;   // RNE
    return (unsigned short)r;
}

// ---- K1: exact fp32 norms -> pre-normalized bf16 rows (wave per row) ------
__global__ __launch_bounds__(128) void norm_kernel(
    const float* __restrict__ feats, unsigned short* __restrict__ nrm)
{
    const int w = threadIdx.x >> 6, l = threadIdx.x & 63;
    const int row = blockIdx.x * 2 + w;
    float4 v = ((const float4*)(feats + (size_t)row * F))[l];   // 64*4 = 256
    float ss = v.x*v.x + v.y*v.y + v.z*v.z + v.w*v.w;
    #pragma unroll
    for (int o = 32; o > 0; o >>= 1) ss += __shfl_xor(ss, o);   // all lanes
    const float inv = 1.f / fmaxf(sqrtf(ss + EPSF), EPSF);
    ushort4 o4 = { f2bf(v.x*inv), f2bf(v.y*inv), f2bf(v.z*inv), f2bf(v.w*inv) };
    ((ushort4*)(nrm + (size_t)row * F))[l] = o4;
}

// ---- K2: cos tile GEMM, 1 wave per 16x16 tile, 1024 blocks ----------------
__global__ __launch_bounds__(64) void cos_mfma(
    const unsigned short* __restrict__ nrm, float* __restrict__ cosm)
{
    const int bid = blockIdx.x;
    const int it = bid >> 5, jt = bid & 31;      // 32x32 tiles of 16x16
    const int l = threadIdx.x;

    __shared__ __align__(16) unsigned char Abf[16 * 512];   // 16 rows x 512 B
    __shared__ __align__(16) unsigned char Bbf[16 * 512];

    // reg-stage panels; XOR-swizzled ds_write (phys chunk = c ^ (row&7))
    const unsigned char* Ag = (const unsigned char*)(nrm + (size_t)(it * 16) * F);
    const unsigned char* Bg = (const unsigned char*)(nrm + (size_t)(jt * 16) * F);
    #pragma unroll
    for (int q = 0; q < 8; ++q) {
        int g = q * 64 + l;          // 16B-chunk id 0..511
        int r = g >> 5;              // row 0..15
        int c = g & 31;              // logical chunk within row
        int p = c ^ (r & 7);         // physical chunk
        uint4 va = *(const uint4*)(Ag + (size_t)g * 16);     // coalesced
        *(uint4*)(Abf + r * 512 + p * 16) = va;
        uint4 vb = *(const uint4*)(Bg + (size_t)g * 16);
        *(uint4*)(Bbf + r * 512 + p * 16) = vb;
    }
    // single wave: compiler inserts the vmcnt/lgkmcnt for this RAW dep chain

    const int row_f = l & 15;        // fragment row (A row / B row)
    const int kg    = l >> 4;        // k-group 0..3
    f32x4 acc = {0.f, 0.f, 0.f, 0.f};
    #pragma unroll
    for (int kc = 0; kc < 8; ++kc) {
        int cc = (kc * 4 + kg) ^ (row_f & 7);
        frag_ab a = *(const frag_ab*)(Abf + row_f * 512 + cc * 16);
        frag_ab b = *(const frag_ab*)(Bbf + row_f * 512 + cc * 16);
        acc = __builtin_amdgcn_mfma_f32_16x16x32_bf16(a, b, acc, 0, 0, 0);
    }
    // C layout (verified): col = lane&15, row = (lane>>4)*4 + j
    const int col = l & 15;
    #pragma unroll
    for (int j = 0; j < 4; ++j) {
        int row = kg * 4 + j;
        cosm[(size_t)(it * 16 + row) * B + jt * 16 + col] = acc[j];
    }
}

// ---- K3: per-row hinge sums + ticket last-block finalize ------------------
__global__ __launch_bounds__(256) void rows_kernel(
    const int* __restrict__ ids, const float* __restrict__ cosm,
    float* __restrict__ rowloss, int* __restrict__ rowvalid,
    unsigned int* __restrict__ ticket, float* __restrict__ out)
{
    const int i    = blockIdx.x;
    const int tid  = threadIdx.x;
    const int lane = tid & 63;
    const int wid  = tid >> 6;

    __shared__ int   dd[B];
    __shared__ float vals[B];
    __shared__ unsigned long long cmask[8];
    __shared__ int   coff[9];
    __shared__ float part_s[4], part_n[4];
    __shared__ int   lastflag;

    const int4 idi = ((const int4*)ids)[i];
    #pragma unroll
    for (int jj = 0; jj < 2; ++jj) {
        int j = tid + jj * 256;
        int4 idj = ((const int4*)ids)[j];
        dd[j] = abs(idi.x - idj.x) + abs(idi.y - idj.y)
              + abs(idi.z - idj.z) + abs(idi.w - idj.w);
    }
    __syncthreads();

    #pragma unroll
    for (int cc = 0; cc < 2; ++cc) {
        int chunk = wid * 2 + cc;
        int j = chunk * 64 + lane;
        unsigned long long m = __ballot((dd[j] == 0) && (j != i));
        if (lane == 0) cmask[chunk] = m;
    }
    __syncthreads();
    if (tid == 0) {
        int a = 0;
        #pragma unroll
        for (int c = 0; c < 8; ++c) { coff[c] = a; a += (int)__popcll(cmask[c]); }
        coff[8] = a;
    }
    __syncthreads();
    #pragma unroll
    for (int cc = 0; cc < 2; ++cc) {
        int chunk = wid * 2 + cc;
        int j = chunk * 64 + lane;
        unsigned long long m = cmask[chunk];
        if ((m >> lane) & 1ull) {
            int pos = coff[chunk] + (int)__popcll(m & ((1ull << lane) - 1ull));
            vals[pos] = cosm[(size_t)i * B + j];
        }
    }
    __syncthreads();

    const int ns = coff[8];
    const int d0 = dd[tid], d1 = dd[tid + 256];
    const bool m0 = d0 > 0, m1 = d1 > 0;
    const float b0 = 0.15f * (float)d0 + cosm[(size_t)i * B + tid];
    const float b1 = 0.15f * (float)d1 + cosm[(size_t)i * B + tid + 256];

    float s = 0.f;
    for (int t = 0; t < ns; ++t) {
        float a = vals[t];
        if (m0) s += fmaxf(0.f, b0 - a);
        if (m1) s += fmaxf(0.f, b1 - a);
    }
    float ndf = (m0 ? 1.f : 0.f) + (m1 ? 1.f : 0.f);

    #pragma unroll
    for (int o = 32; o > 0; o >>= 1) {
        s   += __shfl_down(s, o);
        ndf += __shfl_down(ndf, o);
    }
    if (lane == 0) { part_s[wid] = s; part_n[wid] = ndf; }
    __syncthreads();
    if (tid == 0) {
        float tot = part_s[0] + part_s[1] + part_s[2] + part_s[3];
        float nd  = part_n[0] + part_n[1] + part_n[2] + part_n[3];
        float cnt = (float)ns * nd;
        rowloss[i]  = (cnt > 0.f) ? tot / cnt : 0.f;
        rowvalid[i] = (cnt > 0.f) ? 1 : 0;
        __threadfence();
        unsigned int old = atomicAdd(ticket, 1u);
        lastflag = (old == (unsigned)(B - 1)) ? 1 : 0;
    }
    __syncthreads();
    if (!lastflag) return;

    // last block: deterministic device-coherent reduce over all 512 rows
    float fs = atomicAdd(&rowloss[tid], 0.f) + atomicAdd(&rowloss[tid + 256], 0.f);
    float fv = (float)(atomicAdd(&rowvalid[tid], 0) + atomicAdd(&rowvalid[tid + 256], 0));
    #pragma unroll
    for (int o = 32; o > 0; o >>= 1) { fs += __shfl_down(fs, o); fv += __shfl_down(fv, o); }
    __syncthreads();
    if (lane == 0) { part_s[wid] = fs; part_n[wid] = fv; }
    __syncthreads();
    if (tid == 0) {
        float ts = part_s[0] + part_s[1] + part_s[2] + part_s[3];
        float tv = part_n[0] + part_n[1] + part_n[2] + part_n[3];
        out[0] = ts / fmaxf(tv, 1.f);
    }
}

extern "C" void kernel_launch(void* const* d_in, const int* in_sizes, int n_in,
                              void* d_out, int out_size, void* d_ws, size_t ws_size,
                              hipStream_t stream) {
    const int*   ids   = (const int*)d_in[0];
    const float* feats = (const float*)d_in[1];
    float* out = (float*)d_out;

    char* ws = (char*)d_ws;
    float*          cosm     = (float*)ws;                         // 1 MB
    unsigned short* nrm      = (unsigned short*)(ws + (1u << 20)); // 256 KB
    float*          rowloss  = (float*)(ws + (1u << 20) + (1u << 18));
    int*            rowvalid = (int*)(ws + (1u << 20) + (1u << 18) + 2048);
    unsigned int*   ticket   = (unsigned int*)(ws + (1u << 20) + (1u << 18) + 4096);

    hipMemsetAsync(ticket, 0, sizeof(unsigned int), stream);
    hipLaunchKernelGGL(norm_kernel, dim3(B / 2), dim3(128), 0, stream, feats, nrm);
    hipLaunchKernelGGL(cos_mfma, dim3(32 * 32), dim3(64), 0, stream, nrm, cosm);
    hipLaunchKernelGGL(rows_kernel, dim3(B), dim3(256), 0, stream,
                       ids, cosm, rowloss, rowvalid, ticket, out);
}

// Round 7
// 18.219 us; speedup vs baseline: 2.4938x; 1.6298x over previous
//
#include <hip/hip_runtime.h>
#include <math.h>

#define EPSF 1e-8f

constexpr int B = 512;
constexpr int F = 256;

using frag_ab = __attribute__((ext_vector_type(8))) short;   // 8 bf16
using f32x4   = __attribute__((ext_vector_type(4))) float;

__device__ __forceinline__ unsigned short f2bf(float f) {
    unsigned int u = __float_as_uint(f);
    unsigned int r = (u + 0x7fffu + ((u >> 16) & 1u)) >> 16;   // RNE
    return (unsigned short)r;
}

// ---- K1: exact fp32 norms -> pre-normalized bf16 rows (wave per row) ------
__global__ __launch_bounds__(128) void norm_kernel(
    const float* __restrict__ feats, unsigned short* __restrict__ nrm)
{
    const int w = threadIdx.x >> 6, l = threadIdx.x & 63;
    const int row = blockIdx.x * 2 + w;
    float4 v = ((const float4*)(feats + (size_t)row * F))[l];   // 64*4 = 256
    float ss = v.x*v.x + v.y*v.y + v.z*v.z + v.w*v.w;
    #pragma unroll
    for (int o = 32; o > 0; o >>= 1) ss += __shfl_xor(ss, o);
    const float inv = 1.f / fmaxf(sqrtf(ss + EPSF), EPSF);
    ushort4 o4 = { f2bf(v.x*inv), f2bf(v.y*inv), f2bf(v.z*inv), f2bf(v.w*inv) };
    ((ushort4*)(nrm + (size_t)row * F))[l] = o4;
}

// ---- K2: cos tile GEMM, 1 wave per 16x16 tile, 1024 blocks ----------------
__global__ __launch_bounds__(64) void cos_mfma(
    const unsigned short* __restrict__ nrm, float* __restrict__ cosm)
{
    const int bid = blockIdx.x;
    const int it = bid >> 5, jt = bid & 31;      // 32x32 grid of 16x16 tiles
    const int l = threadIdx.x;

    __shared__ __align__(16) unsigned char Abf[16 * 512];   // 16 rows x 512 B
    __shared__ __align__(16) unsigned char Bbf[16 * 512];

    // reg-stage panels; XOR-swizzled ds_write (phys chunk = c ^ (row&7))
    const unsigned char* Ag = (const unsigned char*)(nrm + (size_t)(it * 16) * F);
    const unsigned char* Bg = (const unsigned char*)(nrm + (size_t)(jt * 16) * F);
    #pragma unroll
    for (int q = 0; q < 8; ++q) {
        int g = q * 64 + l;          // 16B-chunk id 0..511
        int r = g >> 5;              // row 0..15
        int c = g & 31;              // logical chunk within row
        int p = c ^ (r & 7);         // physical chunk
        uint4 va = *(const uint4*)(Ag + (size_t)g * 16);     // coalesced
        *(uint4*)(Abf + r * 512 + p * 16) = va;
        uint4 vb = *(const uint4*)(Bg + (size_t)g * 16);
        *(uint4*)(Bbf + r * 512 + p * 16) = vb;
    }
    // single wave: compiler orders ds_write -> ds_read via lgkmcnt

    const int row_f = l & 15;        // fragment row (A row / B row)
    const int kg    = l >> 4;        // k-group 0..3
    f32x4 acc = {0.f, 0.f, 0.f, 0.f};
    #pragma unroll
    for (int kc = 0; kc < 8; ++kc) {
        int cc = (kc * 4 + kg) ^ (row_f & 7);
        frag_ab a = *(const frag_ab*)(Abf + row_f * 512 + cc * 16);
        frag_ab b = *(const frag_ab*)(Bbf + row_f * 512 + cc * 16);
        acc = __builtin_amdgcn_mfma_f32_16x16x32_bf16(a, b, acc, 0, 0, 0);
    }
    // C layout (verified): col = lane&15, row = (lane>>4)*4 + j
    const int col = l & 15;
    #pragma unroll
    for (int j = 0; j < 4; ++j) {
        int row = kg * 4 + j;
        cosm[(size_t)(it * 16 + row) * B + jt * 16 + col] = acc[j];
    }
}

// ---- K3: per-row hinge sums (R2 verbatim — no atomics/fences) -------------
__global__ __launch_bounds__(256) void rows_kernel(
    const int* __restrict__ ids, const float* __restrict__ cosm,
    float* __restrict__ rowloss, int* __restrict__ rowvalid)
{
    const int i    = blockIdx.x;
    const int tid  = threadIdx.x;
    const int lane = tid & 63;
    const int wid  = tid >> 6;

    __shared__ int   dd[B];
    __shared__ float vals[B];
    __shared__ unsigned long long cmask[8];
    __shared__ int   coff[9];
    __shared__ float part_s[4], part_n[4];

    const int4 idi = ((const int4*)ids)[i];
    #pragma unroll
    for (int jj = 0; jj < 2; ++jj) {
        int j = tid + jj * 256;
        int4 idj = ((const int4*)ids)[j];
        dd[j] = abs(idi.x - idj.x) + abs(idi.y - idj.y)
              + abs(idi.z - idj.z) + abs(idi.w - idj.w);
    }
    __syncthreads();

    #pragma unroll
    for (int cc = 0; cc < 2; ++cc) {
        int chunk = wid * 2 + cc;
        int j = chunk * 64 + lane;
        unsigned long long m = __ballot((dd[j] == 0) && (j != i));
        if (lane == 0) cmask[chunk] = m;
    }
    __syncthreads();
    if (tid == 0) {
        int a = 0;
        #pragma unroll
        for (int c = 0; c < 8; ++c) { coff[c] = a; a += (int)__popcll(cmask[c]); }
        coff[8] = a;
    }
    __syncthreads();
    #pragma unroll
    for (int cc = 0; cc < 2; ++cc) {
        int chunk = wid * 2 + cc;
        int j = chunk * 64 + lane;
        unsigned long long m = cmask[chunk];
        if ((m >> lane) & 1ull) {
            int pos = coff[chunk] + (int)__popcll(m & ((1ull << lane) - 1ull));
            vals[pos] = cosm[(size_t)i * B + j];
        }
    }
    __syncthreads();

    const int ns = coff[8];
    const int d0 = dd[tid], d1 = dd[tid + 256];
    const bool m0 = d0 > 0, m1 = d1 > 0;
    const float b0 = 0.15f * (float)d0 + cosm[(size_t)i * B + tid];
    const float b1 = 0.15f * (float)d1 + cosm[(size_t)i * B + tid + 256];

    float s = 0.f;
    for (int t = 0; t < ns; ++t) {
        float a = vals[t];
        if (m0) s += fmaxf(0.f, b0 - a);
        if (m1) s += fmaxf(0.f, b1 - a);
    }
    float ndf = (m0 ? 1.f : 0.f) + (m1 ? 1.f : 0.f);

    #pragma unroll
    for (int o = 32; o > 0; o >>= 1) {
        s   += __shfl_down(s, o);
        ndf += __shfl_down(ndf, o);
    }
    if (lane == 0) { part_s[wid] = s; part_n[wid] = ndf; }
    __syncthreads();
    if (tid == 0) {
        float tot = part_s[0] + part_s[1] + part_s[2] + part_s[3];
        float nd  = part_n[0] + part_n[1] + part_n[2] + part_n[3];
        float cnt = (float)ns * nd;
        rowloss[i]  = (cnt > 0.f) ? tot / cnt : 0.f;
        rowvalid[i] = (cnt > 0.f) ? 1 : 0;
    }
}

// ---- K4: final mean over valid rows (R2 verbatim) -------------------------
__global__ __launch_bounds__(256) void finalize_kernel(
    const float* __restrict__ rowloss, const int* __restrict__ rowvalid,
    float* __restrict__ out)
{
    const int tid  = threadIdx.x;
    const int lane = tid & 63;
    const int wid  = tid >> 6;
    __shared__ float sb[4], vb[4];

    float s = rowloss[tid] + rowloss[tid + 256];
    float v = (float)(rowvalid[tid] + rowvalid[tid + 256]);
    #pragma unroll
    for (int o = 32; o > 0; o >>= 1) {
        s += __shfl_down(s, o);
        v += __shfl_down(v, o);
    }
    if (lane == 0) { sb[wid] = s; vb[wid] = v; }
    __syncthreads();
    if (tid == 0) {
        float ts = sb[0] + sb[1] + sb[2] + sb[3];
        float tv = vb[0] + vb[1] + vb[2] + vb[3];
        out[0] = ts / fmaxf(tv, 1.f);
    }
}

extern "C" void kernel_launch(void* const* d_in, const int* in_sizes, int n_in,
                              void* d_out, int out_size, void* d_ws, size_t ws_size,
                              hipStream_t stream) {
    const int*   ids   = (const int*)d_in[0];
    const float* feats = (const float*)d_in[1];
    float* out = (float*)d_out;

    char* ws = (char*)d_ws;
    float*          cosm     = (float*)ws;                         // 1 MB
    unsigned short* nrm      = (unsigned short*)(ws + (1u << 20)); // 256 KB
    float*          rowloss  = (float*)(ws + (1u << 20) + (1u << 18));
    int*            rowvalid = (int*)(ws + (1u << 20) + (1u << 18) + 2048);

    hipLaunchKernelGGL(norm_kernel, dim3(B / 2), dim3(128), 0, stream, feats, nrm);
    hipLaunchKernelGGL(cos_mfma, dim3(32 * 32), dim3(64), 0, stream, nrm, cosm);
    hipLaunchKernelGGL(rows_kernel, dim3(B), dim3(256), 0, stream,
                       ids, cosm, rowloss, rowvalid);
    hipLaunchKernelGGL(finalize_kernel, dim3(1), dim3(256), 0, stream,
                       rowloss, rowvalid, out);
}